// Round 1
// baseline (1025.584 us; speedup 1.0000x reference)
//
#include <hip/hip_runtime.h>

// GNN NodeModel for MI355X (gfx950).
// Factored form:
//   A1 = x @ W1[0:32],  A2 = x @ W1[32:64]          (per-node precompute)
//   U1[g] = u[g] @ W1[96:128] + b1                   (64x64 table)
//   msg_e = relu(A1[dest] + A2[src] + ea_e @ W1[64:96] + U1[batch[src]])
//   agg = scatter_sum(msg, dest)                     (HW f32 atomics)
//   P2 = x @ W2[0:32]; U2[g] = u[g] @ W2[96:128] + b2
//   out = relu(P2 + agg @ W2[32:96] + U2[batch])

constexpr int kNodes  = 100000;
constexpr int kEdges  = 1600000;
constexpr int kGraphs = 64;
constexpr int kD      = 32;   // D_NODE = D_EDGE = D_U
constexpr int kOut    = 64;

__device__ __forceinline__ void atomic_add_f32(float* p, float v) {
  // Guarantees global_atomic_add_f32 (no CAS loop) on gfx950.
  unsafeAtomicAdd(p, v);
}

// ---------------------------------------------------------------------------
// U1[g][j] = dot(u[g], W1[96:128][:,j]) + b1[j];  U2 likewise with W2/b2.
__global__ __launch_bounds__(256) void tables_kernel(
    const float* __restrict__ u, const float* __restrict__ W1,
    const float* __restrict__ b1, const float* __restrict__ W2,
    const float* __restrict__ b2, float* __restrict__ U1,
    float* __restrict__ U2) {
  int t = blockIdx.x * 256 + threadIdx.x;
  if (t >= kGraphs * kOut) return;
  int g = t >> 6, j = t & 63;
  float a1 = b1[j], a2 = b2[j];
#pragma unroll
  for (int k = 0; k < kD; ++k) {
    float uv = u[g * kD + k];
    a1 = fmaf(uv, W1[(96 + k) * kOut + j], a1);
    a2 = fmaf(uv, W2[(96 + k) * kOut + j], a2);
  }
  U1[t] = a1;
  U2[t] = a2;
}

// ---------------------------------------------------------------------------
// Per-node precompute: A1 = x@W1a, A2 = x@W1b, P2 = x@W2a.
// One wave per node; lane = output column.
__global__ __launch_bounds__(256) void pre_kernel(
    const float* __restrict__ x, const float* __restrict__ W1,
    const float* __restrict__ W2, float* __restrict__ A1,
    float* __restrict__ A2, float* __restrict__ P2) {
  __shared__ float sWa[kD * kOut];
  __shared__ float sWb[kD * kOut];
  __shared__ float sWp[kD * kOut];
  for (int i = threadIdx.x; i < kD * kOut; i += 256) {
    sWa[i] = W1[i];                 // W1 rows 0..31  (x[dest] block)
    sWb[i] = W1[kD * kOut + i];     // W1 rows 32..63 (x[src] block)
    sWp[i] = W2[i];                 // W2 rows 0..31  (x block)
  }
  __syncthreads();
  const int lane = threadIdx.x & 63;
  const int wave = (blockIdx.x * 256 + threadIdx.x) >> 6;
  const int nw   = gridDim.x * 4;
  for (int n = wave; n < kNodes; n += nw) {
    const float4* xr = reinterpret_cast<const float4*>(x + (size_t)n * kD);
    float a1 = 0.f, a2 = 0.f, p2 = 0.f;
#pragma unroll
    for (int q = 0; q < 8; ++q) {
      float4 v = xr[q];
      int k = q * 4;
      a1 = fmaf(v.x, sWa[(k + 0) * kOut + lane], a1);
      a1 = fmaf(v.y, sWa[(k + 1) * kOut + lane], a1);
      a1 = fmaf(v.z, sWa[(k + 2) * kOut + lane], a1);
      a1 = fmaf(v.w, sWa[(k + 3) * kOut + lane], a1);
      a2 = fmaf(v.x, sWb[(k + 0) * kOut + lane], a2);
      a2 = fmaf(v.y, sWb[(k + 1) * kOut + lane], a2);
      a2 = fmaf(v.z, sWb[(k + 2) * kOut + lane], a2);
      a2 = fmaf(v.w, sWb[(k + 3) * kOut + lane], a2);
      p2 = fmaf(v.x, sWp[(k + 0) * kOut + lane], p2);
      p2 = fmaf(v.y, sWp[(k + 1) * kOut + lane], p2);
      p2 = fmaf(v.z, sWp[(k + 2) * kOut + lane], p2);
      p2 = fmaf(v.w, sWp[(k + 3) * kOut + lane], p2);
    }
    A1[(size_t)n * kOut + lane] = a1;
    A2[(size_t)n * kOut + lane] = a2;
    P2[(size_t)n * kOut + lane] = p2;
  }
}

// ---------------------------------------------------------------------------
// Edge kernel: one wave per edge (grid-stride). lane = output column.
// msg = relu(A1[dest] + A2[src] + ea @ W1c + U1[batch[src]]); atomic scatter.
__global__ __launch_bounds__(256) void edge_kernel(
    const int* __restrict__ ei, const float* __restrict__ ea,
    const int* __restrict__ batch, const float* __restrict__ A1,
    const float* __restrict__ A2, const float* __restrict__ U1,
    const float* __restrict__ W1, float* __restrict__ agg) {
  __shared__ float sW[kD * kOut];
  for (int i = threadIdx.x; i < kD * kOut; i += 256)
    sW[i] = W1[2 * kD * kOut + i];  // W1 rows 64..95 (edge_attr block)
  __syncthreads();
  const int lane = threadIdx.x & 63;
  const int wave = (blockIdx.x * 256 + threadIdx.x) >> 6;
  const int nw   = gridDim.x * 4;
  for (int e = wave; e < kEdges; e += nw) {
    const int s = ei[e];
    const int d = ei[kEdges + e];
    const int g = batch[s];
    float acc = A1[(size_t)d * kOut + lane] + A2[(size_t)s * kOut + lane] +
                U1[g * kOut + lane];
    const float4* er = reinterpret_cast<const float4*>(ea + (size_t)e * kD);
#pragma unroll
    for (int q = 0; q < 8; ++q) {
      float4 v = er[q];
      int k = q * 4;
      acc = fmaf(v.x, sW[(k + 0) * kOut + lane], acc);
      acc = fmaf(v.y, sW[(k + 1) * kOut + lane], acc);
      acc = fmaf(v.z, sW[(k + 2) * kOut + lane], acc);
      acc = fmaf(v.w, sW[(k + 3) * kOut + lane], acc);
    }
    atomic_add_f32(&agg[(size_t)d * kOut + lane], fmaxf(acc, 0.f));
  }
}

// ---------------------------------------------------------------------------
// Node kernel: out = relu(P2 + agg @ W2b + U2[batch]). One wave per node.
__global__ __launch_bounds__(256) void node_kernel(
    const float* __restrict__ P2, const float* __restrict__ agg,
    const int* __restrict__ batch, const float* __restrict__ U2,
    const float* __restrict__ W2, float* __restrict__ out) {
  __shared__ float sW[kOut * kOut];  // W2 rows 32..95 (agg block), 16 KiB
  for (int i = threadIdx.x; i < kOut * kOut; i += 256)
    sW[i] = W2[kD * kOut + i];
  __syncthreads();
  const int lane = threadIdx.x & 63;
  const int wave = (blockIdx.x * 256 + threadIdx.x) >> 6;
  const int nw   = gridDim.x * 4;
  for (int n = wave; n < kNodes; n += nw) {
    const int g = batch[n];
    float acc = P2[(size_t)n * kOut + lane] + U2[g * kOut + lane];
    const float4* ar = reinterpret_cast<const float4*>(agg + (size_t)n * kOut);
#pragma unroll
    for (int q = 0; q < 16; ++q) {
      float4 v = ar[q];
      int k = q * 4;
      acc = fmaf(v.x, sW[(k + 0) * kOut + lane], acc);
      acc = fmaf(v.y, sW[(k + 1) * kOut + lane], acc);
      acc = fmaf(v.z, sW[(k + 2) * kOut + lane], acc);
      acc = fmaf(v.w, sW[(k + 3) * kOut + lane], acc);
    }
    out[(size_t)n * kOut + lane] = fmaxf(acc, 0.f);
  }
}

// ---------------------------------------------------------------------------
extern "C" void kernel_launch(void* const* d_in, const int* in_sizes, int n_in,
                              void* d_out, int out_size, void* d_ws,
                              size_t ws_size, hipStream_t stream) {
  const float* x     = (const float*)d_in[0];
  const int*   ei    = (const int*)d_in[1];   // [2, kEdges], int32 per harness
  const float* ea    = (const float*)d_in[2];
  const float* u     = (const float*)d_in[3];
  const int*   batch = (const int*)d_in[4];
  const float* W1    = (const float*)d_in[5];
  const float* b1    = (const float*)d_in[6];
  const float* W2    = (const float*)d_in[7];
  const float* b2    = (const float*)d_in[8];
  float* out = (float*)d_out;

  // Workspace layout (all f32): A1, A2, P2, agg [kNodes*kOut each], U1, U2.
  float* A1  = (float*)d_ws;
  float* A2  = A1 + (size_t)kNodes * kOut;
  float* P2  = A2 + (size_t)kNodes * kOut;
  float* agg = P2 + (size_t)kNodes * kOut;
  float* U1  = agg + (size_t)kNodes * kOut;
  float* U2  = U1 + kGraphs * kOut;

  hipMemsetAsync(agg, 0, (size_t)kNodes * kOut * sizeof(float), stream);
  tables_kernel<<<(kGraphs * kOut + 255) / 256, 256, 0, stream>>>(
      u, W1, b1, W2, b2, U1, U2);
  pre_kernel<<<1024, 256, 0, stream>>>(x, W1, W2, A1, A2, P2);
  edge_kernel<<<2048, 256, 0, stream>>>(ei, ea, batch, A1, A2, U1, W1, agg);
  node_kernel<<<1024, 256, 0, stream>>>(P2, agg, batch, U2, W2, out);
}